// Round 9
// baseline (179.606 us; speedup 1.0000x reference)
//
#include <hip/hip_runtime.h>
#include <hip/hip_bf16.h>

#define NROWS 12288
#define DDIM  128
#define NT    96      // 12288/128 tiles per dimension
#define CHUNK 4       // j-tiles per block
#define NBLK  1200    // sum_{n=1..96} ceil(n/4) = 4*(1+..+24) = 1200 -> 4.7 blocks/CU, 4 co-resident

typedef __bf16 bf16x8 __attribute__((ext_vector_type(8)));
typedef float  f32x4  __attribute__((ext_vector_type(4)));

__device__ __forceinline__ unsigned short f2bf(float f) {
    union { float f; unsigned u; } a; a.f = f;
    unsigned r = a.u + 0x7fffu + ((a.u >> 16) & 1u);   // RNE to bf16
    return (unsigned short)(r >> 16);
}

// Convert f32 -> bf16 AND permute into fragment-major layout:
// for 16-row block rb, k-chunk ks (16B units c = ks*4+q), lane l = m16 + 16q:
//   xbT ushort offset ((rb*4 + ks)*64 + l) * 8  holds row rb*16+m16, bytes [c*16, c*16+16)
// so every MFMA fragment load is ONE fully-coalesced 1KB global_load_dwordx4.
__global__ void convert_kernel(const float* __restrict__ x, unsigned short* __restrict__ xbT,
                               float* __restrict__ rowsum, float* __restrict__ out) {
    int gid = blockIdx.x * 256 + threadIdx.x;    // 196608 threads, one 16B chunk each
    int e = gid << 3;
    float4 v0 = *(const float4*)(x + e);
    float4 v1 = *(const float4*)(x + e + 4);
    uint4 o;
    o.x = (unsigned)f2bf(v0.x) | ((unsigned)f2bf(v0.y) << 16);
    o.y = (unsigned)f2bf(v0.z) | ((unsigned)f2bf(v0.w) << 16);
    o.z = (unsigned)f2bf(v1.x) | ((unsigned)f2bf(v1.y) << 16);
    o.w = (unsigned)f2bf(v1.z) | ((unsigned)f2bf(v1.w) << 16);
    int r = gid >> 4;          // row  (= e/128)
    int c = gid & 15;          // 16B chunk within row
    size_t off = ((size_t)((r >> 4) * 4 + (c >> 2)) * 64 + (c & 3) * 16 + (r & 15)) * 8;
    *(uint4*)(xbT + off) = o;
    if (gid < NROWS) rowsum[gid] = 0.f;
    if (gid == 0) out[0] = 0.f;
}

// Barrier-free GEMM+exp+rowsum: no LDS staging, no DMA, no per-tile barriers.
// Block = 4 waves over a 128-row band; wave (wr,wc) owns the 64x64 sub-tile
// (rows wr*64, cols wc*64) of each 128x128 tile in the strip. A fragments are
// register-resident across the strip; B fragments are coalesced 1KB loads from
// the L2-resident fragment-major xbT. Waves are fully independent; CHUNK=4
// gives 1200 uniform blocks -> 4 blocks/CU co-resident (16 waves/CU).
__global__ __launch_bounds__(256, 4) void gemm_exp_rowsum(
    const unsigned short* __restrict__ xbT, float* __restrict__ rowsum)
{
    __shared__ float csumS[CHUNK * 128];         // 2 KB col partials

    const int tid = threadIdx.x;

    // decode blockIdx -> (band bi, chunk start jt0)
    int rem = blockIdx.x, bi = 0;
    for (;;) {
        int nch = (NT - bi + CHUNK - 1) / CHUNK;
        if (rem < nch) break;
        rem -= nch; ++bi;
    }
    const int jt0 = bi + rem * CHUNK;
    const int ntiles = min(CHUNK, NT - jt0);
    const int i0 = bi * 128;

    for (int k = tid; k < CHUNK * 128; k += 256) csumS[k] = 0.f;

    const int wave = tid >> 6, lane = tid & 63;
    const int m16 = lane & 15, q = lane >> 4;
    const int wr = wave >> 1, wc = wave & 1;     // 2x2 waves, 64x64 sub-tiles

    // A fragments: row-blocks arb = bi*8 + wr*4 + mi, all ks. 64 VGPR, strip-resident.
    bf16x8 af[4][4];
    #pragma unroll
    for (int mi = 0; mi < 4; ++mi) {
        int arb = bi * 8 + wr * 4 + mi;
        #pragma unroll
        for (int ks = 0; ks < 4; ++ks)
            af[mi][ks] = *(const bf16x8*)(xbT + ((size_t)(arb * 4 + ks) * 64 + lane) * 8);
    }
    __syncthreads();   // csumS zeroed (only barrier before the end)

    // exp(s/T) == exp2(s * invT*log2e)
    const float SCALE = 20.609929155556625f;     // (1/0.07) * log2(e)

    f32x4 rp4[4];
    #pragma unroll
    for (int mi = 0; mi < 4; ++mi) rp4[mi] = (f32x4){0.f, 0.f, 0.f, 0.f};

    for (int t = 0; t < ntiles; ++t) {
        const int jt = jt0 + t;

        // 16 coalesced 1KB fragment loads for this wave's 64 cols x K=128
        const unsigned short* bbase = xbT + (size_t)((jt * 8 + wc * 4) * 4) * 64 * 8;
        bf16x8 bfr[4][4];                        // [ks][ni]
        #pragma unroll
        for (int ks = 0; ks < 4; ++ks)
            #pragma unroll
            for (int ni = 0; ni < 4; ++ni)
                bfr[ks][ni] = *(const bf16x8*)(bbase + ((size_t)(ni * 4 + ks) * 64 + lane) * 8);

        f32x4 acc[4][4] = {};
        #pragma unroll
        for (int ks = 0; ks < 4; ++ks)
            #pragma unroll
            for (int mi = 0; mi < 4; ++mi)
                #pragma unroll
                for (int ni = 0; ni < 4; ++ni)
                    acc[mi][ni] = __builtin_amdgcn_mfma_f32_16x16x32_bf16(
                        af[mi][ks], bfr[ks][ni], acc[mi][ni], 0, 0, 0);

        // C/D layout: col = m16, row = q*4 + r  [verified, absmax=0]
        f32x4 cp4[4];
        #pragma unroll
        for (int ni = 0; ni < 4; ++ni) cp4[ni] = (f32x4){0.f, 0.f, 0.f, 0.f};

        #pragma unroll
        for (int mi = 0; mi < 4; ++mi)
            #pragma unroll
            for (int ni = 0; ni < 4; ++ni) {
                f32x4 sv = acc[mi][ni] * SCALE;
                f32x4 ev;
                ev[0] = __builtin_amdgcn_exp2f(sv[0]);
                ev[1] = __builtin_amdgcn_exp2f(sv[1]);
                ev[2] = __builtin_amdgcn_exp2f(sv[2]);
                ev[3] = __builtin_amdgcn_exp2f(sv[3]);
                rp4[mi] += ev;                   // row partials (register, whole strip)
                cp4[ni] += ev;                   // col partials (this tile)
            }

        if (jt != bi) {                          // diagonal tile: rows only, no double count
            #pragma unroll
            for (int ni = 0; ni < 4; ++ni) {
                float s = (cp4[ni][0] + cp4[ni][1]) + (cp4[ni][2] + cp4[ni][3]);
                s += __shfl_xor(s, 16);
                s += __shfl_xor(s, 32);
                if (q == 0) atomicAdd(&csumS[t * 128 + wc * 64 + ni * 16 + m16], s);
            }
        }
    }

    // row totals: row = i0 + wr*64 + mi*16 + q*4 + r; reduce over the 16 m16-lanes
    #pragma unroll
    for (int mi = 0; mi < 4; ++mi)
        #pragma unroll
        for (int r = 0; r < 4; ++r) {
            float s = rp4[mi][r];
            s += __shfl_xor(s, 1);
            s += __shfl_xor(s, 2);
            s += __shfl_xor(s, 4);
            s += __shfl_xor(s, 8);
            if (m16 == 0) atomicAdd(&rowsum[i0 + wr * 64 + mi * 16 + q * 4 + r], s);
        }

    __syncthreads();   // all csumS LDS atomics visible
    for (int k = tid; k < ntiles * 128; k += 256) {
        float v = csumS[k];
        if (v != 0.f) atomicAdd(&rowsum[jt0 * 128 + k], v);
    }
}

__global__ void finalize_kernel(const float* __restrict__ rowsum, float* __restrict__ out) {
    __shared__ float red[4];
    int gid = blockIdx.x * 256 + threadIdx.x;
    float lg = __logf(rowsum[gid]);
    #pragma unroll
    for (int off = 1; off < 64; off <<= 1)
        lg += __shfl_xor(lg, off);
    const int wv = threadIdx.x >> 6, ln = threadIdx.x & 63;
    if (ln == 0) red[wv] = lg;
    __syncthreads();
    if (threadIdx.x == 0)
        atomicAdd(out, (red[0] + red[1] + red[2] + red[3]) * (1.0f / (float)NROWS));
}

extern "C" void kernel_launch(void* const* d_in, const int* in_sizes, int n_in,
                              void* d_out, int out_size, void* d_ws, size_t ws_size,
                              hipStream_t stream) {
    const float* x = (const float*)d_in[0];
    float* out = (float*)d_out;

    float* rowsum = (float*)d_ws;                                                  // 48 KB
    unsigned short* xbT = (unsigned short*)((char*)d_ws + NROWS * sizeof(float));  // 3 MB bf16, frag-major

    convert_kernel<<<dim3((NROWS * DDIM) / (8 * 256)), dim3(256), 0, stream>>>(x, xbT, rowsum, out);
    gemm_exp_rowsum<<<dim3(NBLK), dim3(256), 0, stream>>>(xbT, rowsum);
    finalize_kernel<<<dim3(NROWS / 256), dim3(256), 0, stream>>>(rowsum, out);
}

// Round 10
// 96.635 us; speedup vs baseline: 1.8586x; 1.8586x over previous
//
#include <hip/hip_runtime.h>
#include <hip/hip_bf16.h>

#define NROWS 12288
#define DDIM  128
#define NT    96      // 12288/128 tiles per dimension
#define NTILE 4656    // NT*(NT+1)/2 upper-tri tiles
#define NBLK  512     // exactly 2 blocks/CU, single round, uniform 9-10 tiles/block
#define MAXT  10

typedef __bf16 bf16x8 __attribute__((ext_vector_type(8)));
typedef float  f32x4  __attribute__((ext_vector_type(4)));

__device__ __forceinline__ unsigned short f2bf(float f) {
    union { float f; unsigned u; } a; a.f = f;
    unsigned r = a.u + 0x7fffu + ((a.u >> 16) & 1u);   // RNE to bf16
    return (unsigned short)(r >> 16);
}

// Convert f32 -> bf16 AND permute into fragment-major layout:
// for 16-row block rb, k-chunk ks (16B units c = ks*4+q), lane l = m16 + 16q:
//   xbT ushort offset ((rb*4 + ks)*64 + l) * 8  holds row rb*16+m16, bytes [c*16, c*16+16)
// so every MFMA fragment load is ONE fully-coalesced 1KB global_load_dwordx4.
__global__ void convert_kernel(const float* __restrict__ x, unsigned short* __restrict__ xbT,
                               float* __restrict__ rowsum, float* __restrict__ out) {
    int gid = blockIdx.x * 256 + threadIdx.x;    // 196608 threads, one 16B chunk each
    int e = gid << 3;
    float4 v0 = *(const float4*)(x + e);
    float4 v1 = *(const float4*)(x + e + 4);
    uint4 o;
    o.x = (unsigned)f2bf(v0.x) | ((unsigned)f2bf(v0.y) << 16);
    o.y = (unsigned)f2bf(v0.z) | ((unsigned)f2bf(v0.w) << 16);
    o.z = (unsigned)f2bf(v1.x) | ((unsigned)f2bf(v1.y) << 16);
    o.w = (unsigned)f2bf(v1.z) | ((unsigned)f2bf(v1.w) << 16);
    int r = gid >> 4;          // row  (= e/128)
    int c = gid & 15;          // 16B chunk within row
    size_t off = ((size_t)((r >> 4) * 4 + (c >> 2)) * 64 + (c & 3) * 16 + (r & 15)) * 8;
    *(uint4*)(xbT + off) = o;
    if (gid < NROWS) rowsum[gid] = 0.f;
    if (gid == 0) out[0] = 0.f;
}

// Barrier-free GEMM+exp+rowsum over a flattened band-major tile list.
// Block b owns tiles [b*4656/512, (b+1)*4656/512) - 9 or 10 tiles, perfectly
// uniform. Wave (wr,wc) computes the 64x64 quadrant of each 128x128 tile.
// A fragments register-resident per band (reloaded on band switch); B frags
// are coalesced 1KB loads from L2-resident fragment-major xbT.
// NOTE: register footprint (~172/wave incl. AGPR) caps this at 2 waves/SIMD -
// do NOT raise launch_bounds to 4 (R9: VGPR 64, 350MB spill traffic, 3x slower).
__global__ __launch_bounds__(256, 2) void gemm_exp_rowsum(
    const unsigned short* __restrict__ xbT, float* __restrict__ rowsum)
{
    __shared__ float csumS[MAXT * 128];          // 5 KB strip-local col partials
    __shared__ int jtArr[MAXT];

    const int tid = threadIdx.x;
    const int g0 = (blockIdx.x * NTILE) >> 9;
    const int g1 = ((blockIdx.x + 1) * NTILE) >> 9;
    const int nt = g1 - g0;                      // 9 or 10

    // decode g0 -> (band bi, tile col jt)
    int bi = 0, rem = g0;
    while (rem >= NT - bi) { rem -= NT - bi; ++bi; }
    int jt = bi + rem;
    const int bi0 = bi, jt0 = jt;

    for (int k = tid; k < MAXT * 128; k += 256) csumS[k] = 0.f;

    const int wave = tid >> 6, lane = tid & 63;
    const int m16 = lane & 15, q = lane >> 4;
    const int wr = wave >> 1, wc = wave & 1;     // 2x2 waves, 64x64 quadrants

    // A fragments for current band: row-blocks arb = bi*8 + wr*4 + mi. 64 VGPR.
    bf16x8 af[4][4];
    #define LOAD_AF() do {                                                       \
        _Pragma("unroll")                                                        \
        for (int mi = 0; mi < 4; ++mi) {                                         \
            int arb = bi * 8 + wr * 4 + mi;                                      \
            _Pragma("unroll")                                                    \
            for (int ks = 0; ks < 4; ++ks)                                       \
                af[mi][ks] = *(const bf16x8*)(xbT + ((size_t)(arb * 4 + ks) * 64 + lane) * 8); \
        }                                                                        \
    } while (0)

    LOAD_AF();
    __syncthreads();   // csumS zeroed (only barrier until writeout)

    // exp(s/T) == exp2(s * invT*log2e)
    const float SCALE = 20.609929155556625f;     // (1/0.07) * log2(e)

    f32x4 rp4[4];
    #pragma unroll
    for (int mi = 0; mi < 4; ++mi) rp4[mi] = (f32x4){0.f, 0.f, 0.f, 0.f};

    // flush row partials of current band to global (atomic), then rezero
    #define FLUSH_RP() do {                                                      \
        _Pragma("unroll")                                                        \
        for (int mi = 0; mi < 4; ++mi) {                                         \
            _Pragma("unroll")                                                    \
            for (int r = 0; r < 4; ++r) {                                        \
                float s = rp4[mi][r];                                            \
                s += __shfl_xor(s, 1);                                           \
                s += __shfl_xor(s, 2);                                           \
                s += __shfl_xor(s, 4);                                           \
                s += __shfl_xor(s, 8);                                           \
                if (m16 == 0)                                                    \
                    atomicAdd(&rowsum[bi * 128 + wr * 64 + mi * 16 + q * 4 + r], s); \
            }                                                                    \
            rp4[mi] = (f32x4){0.f, 0.f, 0.f, 0.f};                               \
        }                                                                        \
    } while (0)

    for (int t = 0; t < nt; ++t) {
        // 16 coalesced 1KB fragment loads: this wave's 64 cols x K=128
        const unsigned short* bbase = xbT + (size_t)((jt * 8 + wc * 4) * 4) * 64 * 8;
        bf16x8 bfr[4][4];                        // [ks][ni]
        #pragma unroll
        for (int ks = 0; ks < 4; ++ks)
            #pragma unroll
            for (int ni = 0; ni < 4; ++ni)
                bfr[ks][ni] = *(const bf16x8*)(bbase + ((size_t)(ni * 4 + ks) * 64 + lane) * 8);

        f32x4 acc[4][4] = {};
        #pragma unroll
        for (int ks = 0; ks < 4; ++ks)
            #pragma unroll
            for (int mi = 0; mi < 4; ++mi)
                #pragma unroll
                for (int ni = 0; ni < 4; ++ni)
                    acc[mi][ni] = __builtin_amdgcn_mfma_f32_16x16x32_bf16(
                        af[mi][ks], bfr[ks][ni], acc[mi][ni], 0, 0, 0);

        // C/D layout: col = m16, row = q*4 + r  [verified, absmax=0]
        f32x4 cp4[4];
        #pragma unroll
        for (int ni = 0; ni < 4; ++ni) cp4[ni] = (f32x4){0.f, 0.f, 0.f, 0.f};

        #pragma unroll
        for (int mi = 0; mi < 4; ++mi)
            #pragma unroll
            for (int ni = 0; ni < 4; ++ni) {
                f32x4 sv = acc[mi][ni] * SCALE;
                f32x4 ev;
                ev[0] = __builtin_amdgcn_exp2f(sv[0]);
                ev[1] = __builtin_amdgcn_exp2f(sv[1]);
                ev[2] = __builtin_amdgcn_exp2f(sv[2]);
                ev[3] = __builtin_amdgcn_exp2f(sv[3]);
                rp4[mi] += ev;                   // row partials (register, per band)
                cp4[ni] += ev;                   // col partials (this tile)
            }

        if (jt != bi) {                          // diagonal tile: rows only, no double count
            #pragma unroll
            for (int ni = 0; ni < 4; ++ni) {
                float s = (cp4[ni][0] + cp4[ni][1]) + (cp4[ni][2] + cp4[ni][3]);
                s += __shfl_xor(s, 16);
                s += __shfl_xor(s, 32);
                if (q == 0) atomicAdd(&csumS[t * 128 + wc * 64 + ni * 16 + m16], s);
            }
        }

        // advance the band-major walk
        if (t + 1 < nt) {
            ++jt;
            if (jt == NT) {                      // band switch (block-uniform)
                FLUSH_RP();
                ++bi; jt = bi;
                LOAD_AF();
            }
        }
    }
    FLUSH_RP();

    // writeout col partials: jt per strip slot t
    if (tid == 0) {
        int bb = bi0, jj = jt0;
        for (int t = 0; t < nt; ++t) {
            jtArr[t] = jj;
            ++jj; if (jj == NT) { ++bb; jj = bb; }
        }
    }
    __syncthreads();   // csumS atomics + jtArr visible
    for (int k = tid; k < nt * 128; k += 256) {
        float v = csumS[k];
        if (v != 0.f) atomicAdd(&rowsum[jtArr[k >> 7] * 128 + (k & 127)], v);
    }
    #undef LOAD_AF
    #undef FLUSH_RP
}

__global__ void finalize_kernel(const float* __restrict__ rowsum, float* __restrict__ out) {
    __shared__ float red[4];
    int gid = blockIdx.x * 256 + threadIdx.x;
    float lg = __logf(rowsum[gid]);
    #pragma unroll
    for (int off = 1; off < 64; off <<= 1)
        lg += __shfl_xor(lg, off);
    const int wv = threadIdx.x >> 6, ln = threadIdx.x & 63;
    if (ln == 0) red[wv] = lg;
    __syncthreads();
    if (threadIdx.x == 0)
        atomicAdd(out, (red[0] + red[1] + red[2] + red[3]) * (1.0f / (float)NROWS));
}

extern "C" void kernel_launch(void* const* d_in, const int* in_sizes, int n_in,
                              void* d_out, int out_size, void* d_ws, size_t ws_size,
                              hipStream_t stream) {
    const float* x = (const float*)d_in[0];
    float* out = (float*)d_out;

    float* rowsum = (float*)d_ws;                                                  // 48 KB
    unsigned short* xbT = (unsigned short*)((char*)d_ws + NROWS * sizeof(float));  // 3 MB bf16, frag-major

    convert_kernel<<<dim3((NROWS * DDIM) / (8 * 256)), dim3(256), 0, stream>>>(x, xbT, rowsum, out);
    gemm_exp_rowsum<<<dim3(NBLK), dim3(256), 0, stream>>>(xbT, rowsum);
    finalize_kernel<<<dim3(NROWS / 256), dim3(256), 0, stream>>>(rowsum, out);
}